// Round 6
// baseline (220.193 us; speedup 1.0000x reference)
//
#include <hip/hip_runtime.h>

// BidirectionalCrossAttention on gfx950.
// R6: flash = 512-thr blocks, 8 waves: S^T phase (h-half x 32j-slice, exact
// coverage) -> barrier -> PV phase (d-half x j-half) with partial-O
// accumulators + one end-of-kernel LDS reduction. K/CV staged with
// global_load_lds + XOR swizzle (no staging regs/ds_writes); Ps padded, b64
// writes. 16 waves/CU (2 blocks x 8 waves), VGPR target <=128.
// prep/gemms unchanged from R3.

typedef _Float16 half_t;
typedef __attribute__((ext_vector_type(4))) _Float16 half4v;
typedef __attribute__((ext_vector_type(8))) _Float16 half8v;
typedef __attribute__((ext_vector_type(4))) float floatx4;

#define MFMA16(a, b, c) __builtin_amdgcn_mfma_f32_16x16x32_f16((a), (b), (c), 0, 0, 0)

#if defined(__has_builtin)
#if __has_builtin(__builtin_amdgcn_exp2f)
#define EXP2F(x) __builtin_amdgcn_exp2f(x)
#else
#define EXP2F(x) exp2f(x)
#endif
#else
#define EXP2F(x) exp2f(x)
#endif

__device__ __forceinline__ void gld16(const half_t* g, half_t* l) {
    __builtin_amdgcn_global_load_lds(
        (const __attribute__((address_space(1))) void*)g,
        (__attribute__((address_space(3))) void*)l, 16, 0, 0);
}

// ---------------------------------------------------------------------------
// prep: blocks 0..2047 = LayerNorm; 2048..2143 = weight fp32 -> fp16 transpose
// ---------------------------------------------------------------------------
__global__ __launch_bounds__(256) void prep_kernel(
    const float* __restrict__ x, const float* __restrict__ ctx,
    const float* __restrict__ gx, const float* __restrict__ bx,
    const float* __restrict__ gc, const float* __restrict__ bc,
    half_t* __restrict__ xn, half_t* __restrict__ cn,
    const float* __restrict__ W0, const float* __restrict__ W1,
    const float* __restrict__ W2, const float* __restrict__ W3,
    const float* __restrict__ W4, const float* __restrict__ W5,
    half_t* __restrict__ Wt)
{
    __shared__ alignas(16) half_t Ts[128][136];
    const int blk = blockIdx.x;
    const int tid = threadIdx.x;
    const int wave = tid >> 6, lane = tid & 63;

    if (blk < 2048) {  // -------- LayerNorm path --------
        const int row = blk * 4 + wave;  // 0..8191
        const float *src, *g, *b;
        half_t* dst;
        if (row < 4096) {
            src = x + (size_t)row * 512; g = gx; b = bx; dst = xn + (size_t)row * 512;
        } else {
            const size_t r = (size_t)(row - 4096);
            src = ctx + r * 512; g = gc; b = bc; dst = cn + r * 512;
        }
        const float4 a0 = *(const float4*)(src + lane * 4);
        const float4 a1 = *(const float4*)(src + 256 + lane * 4);
        float s = a0.x + a0.y + a0.z + a0.w + a1.x + a1.y + a1.z + a1.w;
        float q = a0.x * a0.x + a0.y * a0.y + a0.z * a0.z + a0.w * a0.w +
                  a1.x * a1.x + a1.y * a1.y + a1.z * a1.z + a1.w * a1.w;
#pragma unroll
        for (int m = 1; m < 64; m <<= 1) {
            s += __shfl_xor(s, m);
            q += __shfl_xor(q, m);
        }
        const float mean = s * (1.0f / 512.0f);
        const float var = q * (1.0f / 512.0f) - mean * mean;
        const float rs = rsqrtf(var + 1e-5f);
        const float4 g0 = *(const float4*)(g + lane * 4);
        const float4 g1 = *(const float4*)(g + 256 + lane * 4);
        const float4 b0 = *(const float4*)(b + lane * 4);
        const float4 b1 = *(const float4*)(b + 256 + lane * 4);
        half4v h0, h1;
        h0[0] = (half_t)((a0.x - mean) * rs * g0.x + b0.x);
        h0[1] = (half_t)((a0.y - mean) * rs * g0.y + b0.y);
        h0[2] = (half_t)((a0.z - mean) * rs * g0.z + b0.z);
        h0[3] = (half_t)((a0.w - mean) * rs * g0.w + b0.w);
        h1[0] = (half_t)((a1.x - mean) * rs * g1.x + b1.x);
        h1[1] = (half_t)((a1.y - mean) * rs * g1.y + b1.y);
        h1[2] = (half_t)((a1.z - mean) * rs * g1.z + b1.z);
        h1[3] = (half_t)((a1.w - mean) * rs * g1.w + b1.w);
        *(half4v*)(dst + lane * 4) = h0;
        *(half4v*)(dst + 256 + lane * 4) = h1;
        return;
    }

    // -------- weight transpose path --------
    const int b2 = blk - 2048;          // 0..95
    const int mat = b2 >> 4, tile = b2 & 15;
    const float* src;
    switch (mat) {
        case 0: src = W0; break;
        case 1: src = W1; break;
        case 2: src = W2; break;
        case 3: src = W3; break;
        case 4: src = W4; break;
        default: src = W5; break;
    }
    const int tr0 = (tile >> 2) * 128;  // k base
    const int tc0 = (tile & 3) * 128;   // n base
#pragma unroll
    for (int p = 0; p < 16; ++p) {
        const int idx = p * 256 + tid;
        const int r = idx >> 5, c4 = (idx & 31) * 4;
        const float4 w = *(const float4*)(src + (size_t)(tr0 + r) * 512 + tc0 + c4);
        Ts[c4 + 0][r] = (half_t)w.x;
        Ts[c4 + 1][r] = (half_t)w.y;
        Ts[c4 + 2][r] = (half_t)w.z;
        Ts[c4 + 3][r] = (half_t)w.w;
    }
    __syncthreads();
    half_t* dst = Wt + (size_t)mat * 262144;
#pragma unroll
    for (int p = 0; p < 8; ++p) {
        const int idx = p * 256 + tid;
        const int row = idx >> 4, ch = (idx & 15) * 8;
        *(half8v*)(dst + (size_t)(tc0 + row) * 512 + tr0 + ch) = *(const half8v*)&Ts[row][ch];
    }
}

// ---------------------------------------------------------------------------
// Input projections (unchanged from R3)
// ---------------------------------------------------------------------------
__global__ __launch_bounds__(256) void gemm_in_kernel(
    const half_t* __restrict__ xn, const half_t* __restrict__ cn,
    const half_t* __restrict__ Wt,
    half_t* __restrict__ qk, half_t* __restrict__ v_t,
    half_t* __restrict__ cqk, half_t* __restrict__ cv_t)
{
    const half_t* A; const half_t* B; half_t* O;
    switch (blockIdx.z) {
        case 0:  A = xn; B = Wt;          O = qk;   break;
        case 1:  A = xn; B = Wt + 262144; O = v_t;  break;
        case 2:  A = cn; B = Wt + 524288; O = cqk;  break;
        default: A = cn; B = Wt + 786432; O = cv_t; break;
    }
    const int tr = blockIdx.z & 1;
    const int mt0 = blockIdx.x * 128;   // data rows
    const int nt0 = blockIdx.y * 128;   // weight cols

    __shared__ alignas(16) half_t As[128 * 64];
    __shared__ alignas(16) half_t Ws[128 * 64];

    const int tid = threadIdx.x;
    const int wave = tid >> 6, lane = tid & 63;
    const int wr = wave >> 1, wc = wave & 1;
    const int q4 = lane >> 4, c = lane & 15;

    int srow[4], scol[4];
#pragma unroll
    for (int p = 0; p < 4; ++p) {
        const int ofs = p * 4096 + wave * 1024 + lane * 16;  // bytes in tile
        const int row = ofs >> 7;
        const int pc = (ofs >> 4) & 7;
        srow[p] = row;
        scol[p] = (pc ^ (row & 7)) * 8;
    }

    const half_t* P1 = tr ? As : Ws;   // m-operand tile
    const half_t* P2 = tr ? Ws : As;   // n-operand tile

    const floatx4 z4 = {0.f, 0.f, 0.f, 0.f};
    floatx4 acc[4][4];
#pragma unroll
    for (int mt = 0; mt < 4; ++mt)
#pragma unroll
        for (int nt = 0; nt < 4; ++nt) acc[mt][nt] = z4;

    for (int kb = 0; kb < 8; ++kb) {
        const int k0 = kb * 64;
#pragma unroll
        for (int p = 0; p < 4; ++p) {
            const int lofs = p * 2048 + wave * 512;
            gld16(A + (size_t)(mt0 + srow[p]) * 512 + k0 + scol[p], As + lofs);
            gld16(B + (size_t)(nt0 + srow[p]) * 512 + k0 + scol[p], Ws + lofs);
        }
        __syncthreads();
#pragma unroll
        for (int kt = 0; kt < 2; ++kt) {
            half8v f1[4], f2[4];
#pragma unroll
            for (int i = 0; i < 4; ++i) {
                const int r1 = wr * 64 + i * 16 + c;
                const int r2 = wc * 64 + i * 16 + c;
                f1[i] = *(const half8v*)&P1[(r1 << 6) + (((kt * 4 + q4) ^ (r1 & 7)) << 3)];
                f2[i] = *(const half8v*)&P2[(r2 << 6) + (((kt * 4 + q4) ^ (r2 & 7)) << 3)];
            }
#pragma unroll
            for (int mt = 0; mt < 4; ++mt)
#pragma unroll
                for (int nt = 0; nt < 4; ++nt)
                    acc[mt][nt] = MFMA16(f1[mt], f2[nt], acc[mt][nt]);
        }
        __syncthreads();
    }

    const int bb = mt0 >> 11;
    const int nnb = mt0 & 2047;
    if (tr) {
#pragma unroll
        for (int mt = 0; mt < 4; ++mt) {
            const int row = nnb + wr * 64 + mt * 16 + q4 * 4;
#pragma unroll
            for (int nt = 0; nt < 4; ++nt) {
                const int col = nt0 + wc * 64 + nt * 16 + c;
                const int h = col >> 6, dd = col & 63;
                half4v pk;
                pk[0] = (half_t)acc[mt][nt][0];
                pk[1] = (half_t)acc[mt][nt][1];
                pk[2] = (half_t)acc[mt][nt][2];
                pk[3] = (half_t)acc[mt][nt][3];
                *(half4v*)(O + ((size_t)(bb * 8 + h) * 64 + dd) * 2048 + row) = pk;
            }
        }
    } else {
#pragma unroll
        for (int mt = 0; mt < 4; ++mt) {
            const int colw = nt0 + wr * 64 + mt * 16 + q4 * 4;
            const int h = colw >> 6, dd = colw & 63;
#pragma unroll
            for (int nt = 0; nt < 4; ++nt) {
                const int row = nnb + wc * 64 + nt * 16 + c;
                half4v pk;
                pk[0] = (half_t)acc[mt][nt][0];
                pk[1] = (half_t)acc[mt][nt][1];
                pk[2] = (half_t)acc[mt][nt][2];
                pk[3] = (half_t)acc[mt][nt][3];
                *(half4v*)(O + ((size_t)(bb * 8 + h) * 2048 + row) * 64 + dd) = pk;
            }
        }
    }
}

// ---------------------------------------------------------------------------
// Bidirectional flash attention. grid (16 bh, 16 it, 2 dir), 512 threads.
// 8 waves: S-phase wave (h = w>>2, slice sl = w&3) computes S^T for
// i in h*64+[0,64), j in sl*32+[0,32); PV-phase wave (h, jq=(w>>1)&1, dh=w&1)
// accumulates O^T[d in dh*32+[0,32)][i in h*64+[0,64)] partial over
// j in jq*64+[0,64). End: one LDS reduction over jq + l-exchange.
// ---------------------------------------------------------------------------
__global__ __launch_bounds__(512, 4) void flash_kernel(
    const half_t* __restrict__ qk, const half_t* __restrict__ cqk,
    const half_t* __restrict__ v_t, const half_t* __restrict__ cv_t,
    half_t* __restrict__ out_h, half_t* __restrict__ ctx_out_h)
{
    const int bh = blockIdx.x, it = blockIdx.y, dir = blockIdx.z;
    const half_t* Q  = dir ? cqk : qk;
    const half_t* K  = dir ? qk  : cqk;
    const half_t* VT = dir ? v_t : cv_t;
    half_t* Out = dir ? ctx_out_h : out_h;
    const half_t* Qb = Q + (size_t)bh * (2048 * 64);
    const half_t* Kb = K + (size_t)bh * (2048 * 64);
    const half_t* VTb = VT + (size_t)bh * (64 * 2048);

    // LDS: Ks 128x64 unpadded+XOR (16384 B) | CVs 64x128 unpadded+XOR (16384 B)
    //      Ps 128x132 padded (33792 B) -> 66560 B total, 2 blocks/CU
    __shared__ alignas(16) char smem[66560];
    half_t* Ks  = (half_t*)smem;            // [row j 0..127][64 k], chunk^=(row&7)
    half_t* CVs = (half_t*)(smem + 16384);  // [row d 0..63][128 j], chunk^=(row&15)
    half_t* Ps  = (half_t*)(smem + 32768);  // [i 0..127][132]

    const int tid = threadIdx.x;
    const int wave = tid >> 6, lane = tid & 63;
    const int q4 = lane >> 4, c = lane & 15;
    const int h = wave >> 2;          // i-half
    const int sl = wave & 3;          // S-phase j-slice (32 j)
    const int jq = (wave >> 1) & 1;   // PV j-half
    const int dh = wave & 1;          // PV d-half

    // ones A-fragment (row m==0 all ones) -> l row
    half8v onesb;
#pragma unroll
    for (int j = 0; j < 8; ++j) onesb[j] = (c == 0) ? (half_t)1.0f : (half_t)0.0f;

    // Q fragments: 64 rows per wave (i-half h), pre-scaled by SCALE*log2(e)
    half8v qf[4][2];
#pragma unroll
    for (int mt = 0; mt < 4; ++mt)
#pragma unroll
        for (int kt = 0; kt < 2; ++kt) {
            half8v v = *(const half8v*)(Qb + (size_t)(it * 128 + h * 64 + mt * 16 + c) * 64 +
                                        kt * 32 + q4 * 8);
            qf[mt][kt] = v * (half_t)0.18033688f;
        }

    const floatx4 z4 = {0.f, 0.f, 0.f, 0.f};
    floatx4 accT[2][4];   // [vt (d within half)][mt (i tiles)]
    floatx4 accL[4];      // l partial (dh==0 waves only meaningful)
#pragma unroll
    for (int vt = 0; vt < 2; ++vt)
#pragma unroll
        for (int mt = 0; mt < 4; ++mt) accT[vt][mt] = z4;
#pragma unroll
    for (int mt = 0; mt < 4; ++mt) accL[mt] = z4;

    for (int jt = 0; jt < 16; ++jt) {
        __syncthreads();  // all waves done reading previous Ks/CVs/Ps
        // stage K tile (128x64) and CV tile (64x128) via global_load_lds
        {
            const half_t* Kt = Kb + (size_t)jt * 8192;
            const half_t* Vt = VTb + jt * 128;
#pragma unroll
            for (int p = 0; p < 2; ++p) {
                const int idx = p * 512 + tid;
                const int krow = idx >> 3, kch = idx & 7;
                gld16(Kt + krow * 64 + ((kch ^ (krow & 7)) * 8),
                      Ks + (p * 512 + wave * 64) * 8);
                const int vrow = idx >> 4, vch = idx & 15;
                gld16(Vt + (size_t)vrow * 2048 + ((vch ^ (vrow & 15)) * 8),
                      CVs + (p * 512 + wave * 64) * 8);
            }
        }
        __syncthreads();  // staged tile visible (vmcnt drained by compiler)

        // ---- S-phase: S^T for i in h-half, j in slice sl (32 j) ----
#pragma unroll
        for (int nl = 0; nl < 2; ++nl) {
            const int jrow = sl * 32 + nl * 16 + c;   // j row in Ks
            const half8v kf0 = *(const half8v*)&Ks[jrow * 64 + ((q4 ^ (jrow & 7)) * 8)];
            const half8v kf1 = *(const half8v*)&Ks[jrow * 64 + (((4 + q4) ^ (jrow & 7)) * 8)];
            floatx4 st[4];
#pragma unroll
            for (int mt = 0; mt < 4; ++mt) {
                floatx4 t = MFMA16(kf0, qf[mt][0], z4);   // A=K (m=j), B=Q (n=i)
                st[mt] = MFMA16(kf1, qf[mt][1], t);
            }
#pragma unroll
            for (int mt = 0; mt < 4; ++mt) {
                half4v pk;
#pragma unroll
                for (int r = 0; r < 4; ++r)
                    pk[r] = (half_t)EXP2F(fminf(st[mt][r], 15.0f));
                *(half4v*)&Ps[(h * 64 + mt * 16 + c) * 132 + sl * 32 + nl * 16 + q4 * 4] = pk;
            }
        }
        __syncthreads();  // all P quadrants visible

        // ---- PV-phase: O^T[dh-half][h-half] partial over j-half jq ----
#pragma unroll
        for (int ktl = 0; ktl < 2; ++ktl) {
            half8v pf[4], bf[2];
#pragma unroll
            for (int mt = 0; mt < 4; ++mt)
                pf[mt] = *(const half8v*)&Ps[(h * 64 + mt * 16 + c) * 132 +
                                             jq * 64 + ktl * 32 + q4 * 8];
#pragma unroll
            for (int vt = 0; vt < 2; ++vt) {
                const int drow = dh * 32 + vt * 16 + c;
                bf[vt] = *(const half8v*)&CVs[drow * 128 +
                                              (((jq * 8 + ktl * 4 + q4) ^ c) * 8)];
            }
#pragma unroll
            for (int vt = 0; vt < 2; ++vt)
#pragma unroll
                for (int mt = 0; mt < 4; ++mt)
                    accT[vt][mt] = MFMA16(bf[vt], pf[mt], accT[vt][mt]);
            if (dh == 0) {
#pragma unroll
                for (int mt = 0; mt < 4; ++mt)
                    accL[mt] = MFMA16(onesb, pf[mt], accL[mt]);
            }
        }
    }

    // ---- end-of-kernel reduction over jq + l-exchange ----
    float* red = (float*)smem;
    __syncthreads();  // everything read; safe to reuse LDS
    if (jq == 1) {
        const int slot = h * 2 + dh;
#pragma unroll
        for (int vt = 0; vt < 2; ++vt)
#pragma unroll
            for (int mt = 0; mt < 4; ++mt)
                *(floatx4*)&red[slot * 2048 + (vt * 4 + mt) * 256 + lane * 4] = accT[vt][mt];
        if (dh == 0)
#pragma unroll
            for (int mt = 0; mt < 4; ++mt)
                *(floatx4*)&red[8192 + h * 1024 + mt * 256 + lane * 4] = accL[mt];
    }
    __syncthreads();
    if (jq == 0) {
        const int slot = h * 2 + dh;
#pragma unroll
        for (int vt = 0; vt < 2; ++vt)
#pragma unroll
            for (int mt = 0; mt < 4; ++mt) {
                const floatx4 o = *(const floatx4*)&red[slot * 2048 + (vt * 4 + mt) * 256 + lane * 4];
                accT[vt][mt] += o;
            }
        if (dh == 0)
#pragma unroll
            for (int mt = 0; mt < 4; ++mt) {
                const floatx4 o = *(const floatx4*)&red[8192 + h * 1024 + mt * 256 + lane * 4];
                accL[mt] += o;
            }
    }
    __syncthreads();
    // publish l (row 0 of ones-tile: lanes q4==0, reg 0)
    if (jq == 0 && dh == 0 && q4 == 0) {
#pragma unroll
        for (int mt = 0; mt < 4; ++mt)
            red[10240 + h * 64 + mt * 16 + c] = accL[mt][0];
    }
    __syncthreads();
    if (jq == 0) {
        const size_t ob = (size_t)(bh >> 3) * 2048 * 512 + (size_t)(bh & 7) * 64;
#pragma unroll
        for (int mt = 0; mt < 4; ++mt) {
            const float rl = 1.0f / red[10240 + h * 64 + mt * 16 + c];
            const int row = it * 128 + h * 64 + mt * 16 + c;
#pragma unroll
            for (int vt = 0; vt < 2; ++vt) {
                half4v pk;
                pk[0] = (half_t)(accT[vt][mt][0] * rl);
                pk[1] = (half_t)(accT[vt][mt][1] * rl);
                pk[2] = (half_t)(accT[vt][mt][2] * rl);
                pk[3] = (half_t)(accT[vt][mt][3] * rl);
                *(half4v*)(Out + ob + (size_t)row * 512 + dh * 32 + vt * 16 + q4 * 4) = pk;
            }
        }
    }
}

// ---------------------------------------------------------------------------
// Output projections (unchanged from R3)
// ---------------------------------------------------------------------------
__global__ __launch_bounds__(256) void gemm_out_kernel(
    const half_t* __restrict__ out_h, const half_t* __restrict__ ctx_out_h,
    const half_t* __restrict__ Wt,
    const float* __restrict__ bout, const float* __restrict__ bcout,
    float* __restrict__ dout)
{
    const half_t* A; const half_t* B; const float* bias; float* O;
    if (blockIdx.z == 0) { A = out_h;     B = Wt + 1048576; bias = bout;  O = dout; }
    else                 { A = ctx_out_h; B = Wt + 1310720; bias = bcout; O = dout + 2097152; }

    const int mt0 = blockIdx.x * 64;
    const int nt0 = blockIdx.y * 128;

    __shared__ alignas(16) half_t As[64 * 64];
    __shared__ alignas(16) half_t Ws[128 * 64];

    const int tid = threadIdx.x;
    const int wave = tid >> 6, lane = tid & 63;
    const int wr = wave >> 1, wc = wave & 1;
    const int q4 = lane >> 4, c = lane & 15;

    int srow[4], scol[4];
#pragma unroll
    for (int p = 0; p < 4; ++p) {
        const int ofs = p * 4096 + wave * 1024 + lane * 16;
        const int row = ofs >> 7;
        const int pc = (ofs >> 4) & 7;
        srow[p] = row;
        scol[p] = (pc ^ (row & 7)) * 8;
    }

    const floatx4 z4 = {0.f, 0.f, 0.f, 0.f};
    floatx4 acc[4][2];
#pragma unroll
    for (int mt = 0; mt < 4; ++mt)
#pragma unroll
        for (int nt = 0; nt < 2; ++nt) acc[mt][nt] = z4;

    for (int kb = 0; kb < 8; ++kb) {
        const int k0 = kb * 64;
#pragma unroll
        for (int p = 0; p < 4; ++p) {
            const int lofs = p * 2048 + wave * 512;
            gld16(B + (size_t)(nt0 + srow[p]) * 512 + k0 + scol[p], Ws + lofs);
            if (p < 2)
                gld16(A + (size_t)(mt0 + srow[p]) * 512 + k0 + scol[p], As + lofs);
        }
        __syncthreads();
#pragma unroll
        for (int kt = 0; kt < 2; ++kt) {
            half8v f1[4], f2[2];
#pragma unroll
            for (int i = 0; i < 4; ++i) {
                const int r1 = wr * 64 + i * 16 + c;
                f1[i] = *(const half8v*)&Ws[(r1 << 6) + (((kt * 4 + q4) ^ (r1 & 7)) << 3)];
            }
#pragma unroll
            for (int i = 0; i < 2; ++i) {
                const int r2 = wc * 32 + i * 16 + c;
                f2[i] = *(const half8v*)&As[(r2 << 6) + (((kt * 4 + q4) ^ (r2 & 7)) << 3)];
            }
#pragma unroll
            for (int mt = 0; mt < 4; ++mt)
#pragma unroll
                for (int nt = 0; nt < 2; ++nt)
                    acc[mt][nt] = MFMA16(f1[mt], f2[nt], acc[mt][nt]);
        }
        __syncthreads();
    }

#pragma unroll
    for (int mt = 0; mt < 4; ++mt) {
        const int col = nt0 + wr * 64 + mt * 16 + q4 * 4;
        const float4 bv = *(const float4*)(bias + col);
#pragma unroll
        for (int nt = 0; nt < 2; ++nt) {
            const int row = mt0 + wc * 32 + nt * 16 + c;
            float4 o;
            o.x = acc[mt][nt][0] + bv.x;
            o.y = acc[mt][nt][1] + bv.y;
            o.z = acc[mt][nt][2] + bv.z;
            o.w = acc[mt][nt][3] + bv.w;
            *(float4*)(O + (size_t)row * 512 + col) = o;
        }
    }
}

// ---------------------------------------------------------------------------
extern "C" void kernel_launch(void* const* d_in, const int* in_sizes, int n_in,
                              void* d_out, int out_size, void* d_ws, size_t ws_size,
                              hipStream_t stream)
{
    (void)in_sizes; (void)n_in; (void)out_size; (void)ws_size;
    const float* x      = (const float*)d_in[0];
    const float* ctx    = (const float*)d_in[1];
    const float* g_x    = (const float*)d_in[2];
    const float* b_x    = (const float*)d_in[3];
    const float* g_c    = (const float*)d_in[4];
    const float* b_c    = (const float*)d_in[5];
    const float* W_qk   = (const float*)d_in[6];
    const float* W_cqk  = (const float*)d_in[7];
    const float* W_v    = (const float*)d_in[8];
    const float* W_cv   = (const float*)d_in[9];
    const float* W_out  = (const float*)d_in[10];
    const float* b_out  = (const float*)d_in[11];
    const float* W_cout = (const float*)d_in[12];
    const float* b_cout = (const float*)d_in[13];
    float* out = (float*)d_out;

    half_t* ws = (half_t*)d_ws;
    const size_t SEG = 2097152;  // 2*2048*512 halfs = 4 MB
    half_t* xn        = ws;              // seg0: xn, later out_h
    half_t* cn        = ws + 1 * SEG;    // seg1: cn, later ctx_out_h
    half_t* qk        = ws + 2 * SEG;    // [b,h,n,d]
    half_t* cqk       = ws + 3 * SEG;    // [b,h,n,d]
    half_t* v_t       = ws + 4 * SEG;    // [b,h,d,n]
    half_t* cv_t      = ws + 5 * SEG;    // [b,h,d,n]
    half_t* Wt        = ws + 6 * SEG;    // 6 x 512x512 fp16 transposed weights
    half_t* out_h     = xn;              // flash overwrites dead xn
    half_t* ctx_out_h = cn;              // flash overwrites dead cn

    prep_kernel<<<2144, 256, 0, stream>>>(x, ctx, g_x, b_x, g_c, b_c, xn, cn,
                                          W_qk, W_v, W_cqk, W_cv, W_out, W_cout, Wt);
    gemm_in_kernel<<<dim3(32, 4, 4), 256, 0, stream>>>(xn, cn, Wt, qk, v_t, cqk, cv_t);
    flash_kernel<<<dim3(16, 16, 2), 512, 0, stream>>>(qk, cqk, v_t, cv_t, out_h, ctx_out_h);
    gemm_out_kernel<<<dim3(64, 4, 2), 256, 0, stream>>>(out_h, ctx_out_h, Wt, b_out, b_cout, out);
}

// Round 8
// 171.715 us; speedup vs baseline: 1.2823x; 1.2823x over previous
//
#include <hip/hip_runtime.h>

// BidirectionalCrossAttention on gfx950.
// R7b flash (compile fix of R7): no-Ps design. S^T = K*Q^T with PERMUTED
// j-assignment per 32-j group (tile alpha: j = g*32+(m>>2)*8+(m&3), beta: +4)
// so the S^T C-layout registers ARE the PV B-fragment after v_cvt_pkrtz
// packing — P never touches LDS. LDS = Ks(16KB) + CVs(16KB), XOR-swizzled.
// Register-prefetch staging, 2 barriers/jt. 256 thr, 4 waves x 32 i-rows.
// prep/gemms unchanged from R3.

typedef _Float16 half_t;
typedef __attribute__((ext_vector_type(2))) _Float16 half2v;
typedef __attribute__((ext_vector_type(4))) _Float16 half4v;
typedef __attribute__((ext_vector_type(8))) _Float16 half8v;
typedef __attribute__((ext_vector_type(4))) float floatx4;

#define MFMA16(a, b, c) __builtin_amdgcn_mfma_f32_16x16x32_f16((a), (b), (c), 0, 0, 0)

#if defined(__has_builtin)
#if __has_builtin(__builtin_amdgcn_exp2f)
#define EXP2F(x) __builtin_amdgcn_exp2f(x)
#else
#define EXP2F(x) exp2f(x)
#endif
#else
#define EXP2F(x) exp2f(x)
#endif

__device__ __forceinline__ half2v pk2(float a, float b) {
#if defined(__has_builtin) && __has_builtin(__builtin_amdgcn_cvt_pkrtz)
    union { __fp16 __attribute__((ext_vector_type(2))) i; half2v o; } u;
    u.i = __builtin_amdgcn_cvt_pkrtz(a, b);
    return u.o;
#else
    half2v r; r[0] = (half_t)a; r[1] = (half_t)b; return r;
#endif
}

__device__ __forceinline__ void gld16(const half_t* g, half_t* l) {
    __builtin_amdgcn_global_load_lds(
        (const __attribute__((address_space(1))) void*)g,
        (__attribute__((address_space(3))) void*)l, 16, 0, 0);
}

// ---------------------------------------------------------------------------
// prep: blocks 0..2047 = LayerNorm; 2048..2143 = weight fp32 -> fp16 transpose
// ---------------------------------------------------------------------------
__global__ __launch_bounds__(256) void prep_kernel(
    const float* __restrict__ x, const float* __restrict__ ctx,
    const float* __restrict__ gx, const float* __restrict__ bx,
    const float* __restrict__ gc, const float* __restrict__ bc,
    half_t* __restrict__ xn, half_t* __restrict__ cn,
    const float* __restrict__ W0, const float* __restrict__ W1,
    const float* __restrict__ W2, const float* __restrict__ W3,
    const float* __restrict__ W4, const float* __restrict__ W5,
    half_t* __restrict__ Wt)
{
    __shared__ alignas(16) half_t Ts[128][136];
    const int blk = blockIdx.x;
    const int tid = threadIdx.x;
    const int wave = tid >> 6, lane = tid & 63;

    if (blk < 2048) {  // -------- LayerNorm path --------
        const int row = blk * 4 + wave;  // 0..8191
        const float *src, *g, *b;
        half_t* dst;
        if (row < 4096) {
            src = x + (size_t)row * 512; g = gx; b = bx; dst = xn + (size_t)row * 512;
        } else {
            const size_t r = (size_t)(row - 4096);
            src = ctx + r * 512; g = gc; b = bc; dst = cn + r * 512;
        }
        const float4 a0 = *(const float4*)(src + lane * 4);
        const float4 a1 = *(const float4*)(src + 256 + lane * 4);
        float s = a0.x + a0.y + a0.z + a0.w + a1.x + a1.y + a1.z + a1.w;
        float q = a0.x * a0.x + a0.y * a0.y + a0.z * a0.z + a0.w * a0.w +
                  a1.x * a1.x + a1.y * a1.y + a1.z * a1.z + a1.w * a1.w;
#pragma unroll
        for (int m = 1; m < 64; m <<= 1) {
            s += __shfl_xor(s, m);
            q += __shfl_xor(q, m);
        }
        const float mean = s * (1.0f / 512.0f);
        const float var = q * (1.0f / 512.0f) - mean * mean;
        const float rs = rsqrtf(var + 1e-5f);
        const float4 g0 = *(const float4*)(g + lane * 4);
        const float4 g1 = *(const float4*)(g + 256 + lane * 4);
        const float4 b0 = *(const float4*)(b + lane * 4);
        const float4 b1 = *(const float4*)(b + 256 + lane * 4);
        half4v h0, h1;
        h0[0] = (half_t)((a0.x - mean) * rs * g0.x + b0.x);
        h0[1] = (half_t)((a0.y - mean) * rs * g0.y + b0.y);
        h0[2] = (half_t)((a0.z - mean) * rs * g0.z + b0.z);
        h0[3] = (half_t)((a0.w - mean) * rs * g0.w + b0.w);
        h1[0] = (half_t)((a1.x - mean) * rs * g1.x + b1.x);
        h1[1] = (half_t)((a1.y - mean) * rs * g1.y + b1.y);
        h1[2] = (half_t)((a1.z - mean) * rs * g1.z + b1.z);
        h1[3] = (half_t)((a1.w - mean) * rs * g1.w + b1.w);
        *(half4v*)(dst + lane * 4) = h0;
        *(half4v*)(dst + 256 + lane * 4) = h1;
        return;
    }

    // -------- weight transpose path --------
    const int b2 = blk - 2048;          // 0..95
    const int mat = b2 >> 4, tile = b2 & 15;
    const float* src;
    switch (mat) {
        case 0: src = W0; break;
        case 1: src = W1; break;
        case 2: src = W2; break;
        case 3: src = W3; break;
        case 4: src = W4; break;
        default: src = W5; break;
    }
    const int tr0 = (tile >> 2) * 128;  // k base
    const int tc0 = (tile & 3) * 128;   // n base
#pragma unroll
    for (int p = 0; p < 16; ++p) {
        const int idx = p * 256 + tid;
        const int r = idx >> 5, c4 = (idx & 31) * 4;
        const float4 w = *(const float4*)(src + (size_t)(tr0 + r) * 512 + tc0 + c4);
        Ts[c4 + 0][r] = (half_t)w.x;
        Ts[c4 + 1][r] = (half_t)w.y;
        Ts[c4 + 2][r] = (half_t)w.z;
        Ts[c4 + 3][r] = (half_t)w.w;
    }
    __syncthreads();
    half_t* dst = Wt + (size_t)mat * 262144;
#pragma unroll
    for (int p = 0; p < 8; ++p) {
        const int idx = p * 256 + tid;
        const int row = idx >> 4, ch = (idx & 15) * 8;
        *(half8v*)(dst + (size_t)(tc0 + row) * 512 + tr0 + ch) = *(const half8v*)&Ts[row][ch];
    }
}

// ---------------------------------------------------------------------------
// Input projections (unchanged from R3)
// ---------------------------------------------------------------------------
__global__ __launch_bounds__(256) void gemm_in_kernel(
    const half_t* __restrict__ xn, const half_t* __restrict__ cn,
    const half_t* __restrict__ Wt,
    half_t* __restrict__ qk, half_t* __restrict__ v_t,
    half_t* __restrict__ cqk, half_t* __restrict__ cv_t)
{
    const half_t* A; const half_t* B; half_t* O;
    switch (blockIdx.z) {
        case 0:  A = xn; B = Wt;          O = qk;   break;
        case 1:  A = xn; B = Wt + 262144; O = v_t;  break;
        case 2:  A = cn; B = Wt + 524288; O = cqk;  break;
        default: A = cn; B = Wt + 786432; O = cv_t; break;
    }
    const int tr = blockIdx.z & 1;
    const int mt0 = blockIdx.x * 128;   // data rows
    const int nt0 = blockIdx.y * 128;   // weight cols

    __shared__ alignas(16) half_t As[128 * 64];
    __shared__ alignas(16) half_t Ws[128 * 64];

    const int tid = threadIdx.x;
    const int wave = tid >> 6, lane = tid & 63;
    const int wr = wave >> 1, wc = wave & 1;
    const int q4 = lane >> 4, c = lane & 15;

    int srow[4], scol[4];
#pragma unroll
    for (int p = 0; p < 4; ++p) {
        const int ofs = p * 4096 + wave * 1024 + lane * 16;  // bytes in tile
        const int row = ofs >> 7;
        const int pc = (ofs >> 4) & 7;
        srow[p] = row;
        scol[p] = (pc ^ (row & 7)) * 8;
    }

    const half_t* P1 = tr ? As : Ws;   // m-operand tile
    const half_t* P2 = tr ? Ws : As;   // n-operand tile

    const floatx4 z4 = {0.f, 0.f, 0.f, 0.f};
    floatx4 acc[4][4];
#pragma unroll
    for (int mt = 0; mt < 4; ++mt)
#pragma unroll
        for (int nt = 0; nt < 4; ++nt) acc[mt][nt] = z4;

    for (int kb = 0; kb < 8; ++kb) {
        const int k0 = kb * 64;
#pragma unroll
        for (int p = 0; p < 4; ++p) {
            const int lofs = p * 2048 + wave * 512;
            gld16(A + (size_t)(mt0 + srow[p]) * 512 + k0 + scol[p], As + lofs);
            gld16(B + (size_t)(nt0 + srow[p]) * 512 + k0 + scol[p], Ws + lofs);
        }
        __syncthreads();
#pragma unroll
        for (int kt = 0; kt < 2; ++kt) {
            half8v f1[4], f2[4];
#pragma unroll
            for (int i = 0; i < 4; ++i) {
                const int r1 = wr * 64 + i * 16 + c;
                const int r2 = wc * 64 + i * 16 + c;
                f1[i] = *(const half8v*)&P1[(r1 << 6) + (((kt * 4 + q4) ^ (r1 & 7)) << 3)];
                f2[i] = *(const half8v*)&P2[(r2 << 6) + (((kt * 4 + q4) ^ (r2 & 7)) << 3)];
            }
#pragma unroll
            for (int mt = 0; mt < 4; ++mt)
#pragma unroll
                for (int nt = 0; nt < 4; ++nt)
                    acc[mt][nt] = MFMA16(f1[mt], f2[nt], acc[mt][nt]);
        }
        __syncthreads();
    }

    const int bb = mt0 >> 11;
    const int nnb = mt0 & 2047;
    if (tr) {
#pragma unroll
        for (int mt = 0; mt < 4; ++mt) {
            const int row = nnb + wr * 64 + mt * 16 + q4 * 4;
#pragma unroll
            for (int nt = 0; nt < 4; ++nt) {
                const int col = nt0 + wc * 64 + nt * 16 + c;
                const int h = col >> 6, dd = col & 63;
                half4v pk;
                pk[0] = (half_t)acc[mt][nt][0];
                pk[1] = (half_t)acc[mt][nt][1];
                pk[2] = (half_t)acc[mt][nt][2];
                pk[3] = (half_t)acc[mt][nt][3];
                *(half4v*)(O + ((size_t)(bb * 8 + h) * 64 + dd) * 2048 + row) = pk;
            }
        }
    } else {
#pragma unroll
        for (int mt = 0; mt < 4; ++mt) {
            const int colw = nt0 + wr * 64 + mt * 16 + q4 * 4;
            const int h = colw >> 6, dd = colw & 63;
#pragma unroll
            for (int nt = 0; nt < 4; ++nt) {
                const int row = nnb + wc * 64 + nt * 16 + c;
                half4v pk;
                pk[0] = (half_t)acc[mt][nt][0];
                pk[1] = (half_t)acc[mt][nt][1];
                pk[2] = (half_t)acc[mt][nt][2];
                pk[3] = (half_t)acc[mt][nt][3];
                *(half4v*)(O + ((size_t)(bb * 8 + h) * 2048 + row) * 64 + dd) = pk;
            }
        }
    }
}

// ---------------------------------------------------------------------------
// Bidirectional flash attention. grid (16 bh, 16 it, 2 dir), 256 thr, 4 waves
// x 32 i-rows. Per 32-j group g: tile a computes j = g*32+(m>>2)*8+(m&3),
// tile b = +4 (permuted Ks row reads) -> S^T C-regs pack directly into the
// PV B-fragment (k = q4*8+jj). No P in LDS. l via ones A-fragment MFMA.
// ---------------------------------------------------------------------------
__global__ __launch_bounds__(256, 2) void flash_kernel(
    const half_t* __restrict__ qk, const half_t* __restrict__ cqk,
    const half_t* __restrict__ v_t, const half_t* __restrict__ cv_t,
    half_t* __restrict__ out_h, half_t* __restrict__ ctx_out_h)
{
    const int bh = blockIdx.x, it = blockIdx.y, dir = blockIdx.z;
    const half_t* Q  = dir ? cqk : qk;
    const half_t* K  = dir ? qk  : cqk;
    const half_t* VT = dir ? v_t : cv_t;
    half_t* Out = dir ? ctx_out_h : out_h;
    const half_t* Qb = Q + (size_t)bh * (2048 * 64);
    const half_t* Kb = K + (size_t)bh * (2048 * 64);
    const half_t* VTb = VT + (size_t)bh * (64 * 2048);

    // Ks[128 j][64 k], chunk swz = (row>>2)&7 ; CVs[64 d][128 j], swz = row&15
    __shared__ alignas(16) half_t Ks[128 * 64];    // 16384 B
    __shared__ alignas(16) half_t CVs[64 * 128];   // 16384 B

    const int tid = threadIdx.x;
    const int wave = tid >> 6, lane = tid & 63;
    const int q4 = lane >> 4, c = lane & 15;

    // ones A-fragment (m==0 row all-ones) -> l row of O^T
    half8v onesb;
#pragma unroll
    for (int j = 0; j < 8; ++j) onesb[j] = (c == 0) ? (half_t)1.0f : (half_t)0.0f;

    // Q fragments: 32 rows per wave, pre-scaled by SCALE*log2(e)
    half8v qf[2][2];
#pragma unroll
    for (int mt = 0; mt < 2; ++mt)
#pragma unroll
        for (int kt = 0; kt < 2; ++kt) {
            half8v v = *(const half8v*)(Qb + (size_t)(it * 128 + wave * 32 + mt * 16 + c) * 64 +
                                        kt * 32 + q4 * 8);
            qf[mt][kt] = v * (half_t)0.18033688f;
        }

    const floatx4 z4 = {0.f, 0.f, 0.f, 0.f};
    floatx4 accT[4][2];   // [vt d-tiles][mt i-tiles] of O^T
    floatx4 accL[2];      // l row
#pragma unroll
    for (int vt = 0; vt < 4; ++vt)
#pragma unroll
        for (int mt = 0; mt < 2; ++mt) accT[vt][mt] = z4;
    accL[0] = z4; accL[1] = z4;

    // prefetch jt=0 (4 K-chunks + 4 CV-chunks per thread)
    half8v kpre[4], vpre[4];
#pragma unroll
    for (int p = 0; p < 4; ++p) {
        const int cidx = p * 256 + tid;
        kpre[p] = *(const half8v*)(Kb + (size_t)(cidx >> 3) * 64 + (cidx & 7) * 8);
        vpre[p] = *(const half8v*)(VTb + (size_t)(cidx >> 4) * 2048 + (cidx & 15) * 8);
    }

    for (int jt = 0; jt < 16; ++jt) {
        __syncthreads();  // all waves done reading previous Ks/CVs
#pragma unroll
        for (int p = 0; p < 4; ++p) {
            const int cidx = p * 256 + tid;
            const int krow = cidx >> 3, kch = cidx & 7;
            *(half8v*)&Ks[krow * 64 + ((kch ^ ((krow >> 2) & 7)) * 8)] = kpre[p];
            const int vrow = cidx >> 4, vch = cidx & 15;
            *(half8v*)&CVs[vrow * 128 + ((vch ^ (vrow & 15)) * 8)] = vpre[p];
        }
        __syncthreads();  // staged tile visible
        if (jt < 15) {    // prefetch next tile; overlaps compute
            const half_t* Kt = Kb + (size_t)(jt + 1) * 8192;
            const half_t* Vt = VTb + (jt + 1) * 128;
#pragma unroll
            for (int p = 0; p < 4; ++p) {
                const int cidx = p * 256 + tid;
                kpre[p] = *(const half8v*)(Kt + (size_t)(cidx >> 3) * 64 + (cidx & 7) * 8);
                vpre[p] = *(const half8v*)(Vt + (size_t)(cidx >> 4) * 2048 + (cidx & 15) * 8);
            }
        }

#pragma unroll
        for (int g = 0; g < 4; ++g) {
            // ---- S^T for 32-j group g, tiles a (t=0) and b (t=1) ----
            floatx4 st[2][2];   // [mt][t]
#pragma unroll
            for (int t = 0; t < 2; ++t) {
                const int jr = g * 32 + t * 4 + ((c >> 2) << 3) + (c & 3);
                const int sw = (jr >> 2) & 7;
                const half8v kf0 = *(const half8v*)&Ks[jr * 64 + ((q4 ^ sw) * 8)];
                const half8v kf1 = *(const half8v*)&Ks[jr * 64 + (((4 + q4) ^ sw) * 8)];
#pragma unroll
                for (int mt = 0; mt < 2; ++mt) {
                    floatx4 tt = MFMA16(kf0, qf[mt][0], z4);
                    st[mt][t] = MFMA16(kf1, qf[mt][1], tt);
                }
            }
            // ---- exp2 + pack: C-regs -> PV B-fragment, no LDS ----
            half8v pf[2];
#pragma unroll
            for (int mt = 0; mt < 2; ++mt) {
                union { half8v v; half2v h2[4]; } u;
                u.h2[0] = pk2(EXP2F(fminf(st[mt][0][0], 15.0f)),
                              EXP2F(fminf(st[mt][0][1], 15.0f)));
                u.h2[1] = pk2(EXP2F(fminf(st[mt][0][2], 15.0f)),
                              EXP2F(fminf(st[mt][0][3], 15.0f)));
                u.h2[2] = pk2(EXP2F(fminf(st[mt][1][0], 15.0f)),
                              EXP2F(fminf(st[mt][1][1], 15.0f)));
                u.h2[3] = pk2(EXP2F(fminf(st[mt][1][2], 15.0f)),
                              EXP2F(fminf(st[mt][1][3], 15.0f)));
                pf[mt] = u.v;
            }
            // ---- PV: O^T += CV * P^T ----
#pragma unroll
            for (int vt = 0; vt < 4; ++vt) {
                const half8v bf = *(const half8v*)&CVs[(vt * 16 + c) * 128 +
                                                       (((g * 4 + q4) ^ c) * 8)];
#pragma unroll
                for (int mt = 0; mt < 2; ++mt)
                    accT[vt][mt] = MFMA16(bf, pf[mt], accT[vt][mt]);
            }
#pragma unroll
            for (int mt = 0; mt < 2; ++mt)
                accL[mt] = MFMA16(onesb, pf[mt], accL[mt]);
        }
    }

    // epilogue: O^T C-layout: i = c, d = vt*16 + q4*4 + r; /l; half4 along d
    const size_t ob = (size_t)(bh >> 3) * 2048 * 512 + (size_t)(bh & 7) * 64;
#pragma unroll
    for (int mt = 0; mt < 2; ++mt) {
        const float l = __shfl(accL[mt][0], c);  // l[i=c] lives in lane c (q4=0), reg 0
        const float rl = 1.0f / l;
        const int row = it * 128 + wave * 32 + mt * 16 + c;
#pragma unroll
        for (int vt = 0; vt < 4; ++vt) {
            half4v pk;
            pk[0] = (half_t)(accT[vt][mt][0] * rl);
            pk[1] = (half_t)(accT[vt][mt][1] * rl);
            pk[2] = (half_t)(accT[vt][mt][2] * rl);
            pk[3] = (half_t)(accT[vt][mt][3] * rl);
            *(half4v*)(Out + ob + (size_t)row * 512 + vt * 16 + q4 * 4) = pk;
        }
    }
}

// ---------------------------------------------------------------------------
// Output projections (unchanged from R3)
// ---------------------------------------------------------------------------
__global__ __launch_bounds__(256) void gemm_out_kernel(
    const half_t* __restrict__ out_h, const half_t* __restrict__ ctx_out_h,
    const half_t* __restrict__ Wt,
    const float* __restrict__ bout, const float* __restrict__ bcout,
    float* __restrict__ dout)
{
    const half_t* A; const half_t* B; const float* bias; float* O;
    if (blockIdx.z == 0) { A = out_h;     B = Wt + 1048576; bias = bout;  O = dout; }
    else                 { A = ctx_out_h; B = Wt + 1310720; bias = bcout; O = dout + 2097152; }

    const int mt0 = blockIdx.x * 64;
    const int nt0 = blockIdx.y * 128;

    __shared__ alignas(16) half_t As[64 * 64];
    __shared__ alignas(16) half_t Ws[128 * 64];

    const int tid = threadIdx.x;
    const int wave = tid >> 6, lane = tid & 63;
    const int wr = wave >> 1, wc = wave & 1;
    const int q4 = lane >> 4, c = lane & 15;

    int srow[4], scol[4];
#pragma unroll
    for (int p = 0; p < 4; ++p) {
        const int ofs = p * 4096 + wave * 1024 + lane * 16;
        const int row = ofs >> 7;
        const int pc = (ofs >> 4) & 7;
        srow[p] = row;
        scol[p] = (pc ^ (row & 7)) * 8;
    }

    const floatx4 z4 = {0.f, 0.f, 0.f, 0.f};
    floatx4 acc[4][2];
#pragma unroll
    for (int mt = 0; mt < 4; ++mt)
#pragma unroll
        for (int nt = 0; nt < 2; ++nt) acc[mt][nt] = z4;

    for (int kb = 0; kb < 8; ++kb) {
        const int k0 = kb * 64;
#pragma unroll
        for (int p = 0; p < 4; ++p) {
            const int lofs = p * 2048 + wave * 512;
            gld16(B + (size_t)(nt0 + srow[p]) * 512 + k0 + scol[p], Ws + lofs);
            if (p < 2)
                gld16(A + (size_t)(mt0 + srow[p]) * 512 + k0 + scol[p], As + lofs);
        }
        __syncthreads();
#pragma unroll
        for (int kt = 0; kt < 2; ++kt) {
            half8v f1[4], f2[2];
#pragma unroll
            for (int i = 0; i < 4; ++i) {
                const int r1 = wr * 64 + i * 16 + c;
                f1[i] = *(const half8v*)&Ws[(r1 << 6) + (((kt * 4 + q4) ^ (r1 & 7)) << 3)];
            }
#pragma unroll
            for (int i = 0; i < 2; ++i) {
                const int r2 = wc * 32 + i * 16 + c;
                f2[i] = *(const half8v*)&As[(r2 << 6) + (((kt * 4 + q4) ^ (r2 & 7)) << 3)];
            }
#pragma unroll
            for (int mt = 0; mt < 4; ++mt)
#pragma unroll
                for (int nt = 0; nt < 2; ++nt)
                    acc[mt][nt] = MFMA16(f1[mt], f2[nt], acc[mt][nt]);
        }
        __syncthreads();
    }

#pragma unroll
    for (int mt = 0; mt < 4; ++mt) {
        const int col = nt0 + wr * 64 + mt * 16 + q4 * 4;
        const float4 bv = *(const float4*)(bias + col);
#pragma unroll
        for (int nt = 0; nt < 2; ++nt) {
            const int row = mt0 + wc * 32 + nt * 16 + c;
            float4 o;
            o.x = acc[mt][nt][0] + bv.x;
            o.y = acc[mt][nt][1] + bv.y;
            o.z = acc[mt][nt][2] + bv.z;
            o.w = acc[mt][nt][3] + bv.w;
            *(float4*)(O + (size_t)row * 512 + col) = o;
        }
    }
}

// ---------------------------------------------------------------------------
extern "C" void kernel_launch(void* const* d_in, const int* in_sizes, int n_in,
                              void* d_out, int out_size, void* d_ws, size_t ws_size,
                              hipStream_t stream)
{
    (void)in_sizes; (void)n_in; (void)out_size; (void)ws_size;
    const float* x      = (const float*)d_in[0];
    const float* ctx    = (const float*)d_in[1];
    const float* g_x    = (const float*)d_in[2];
    const float* b_x    = (const float*)d_in[3];
    const float* g_c    = (const float*)d_in[4];
    const float* b_c    = (const float*)d_in[5];
    const float* W_qk   = (const float*)d_in[6];
    const float* W_cqk  = (const float*)d_in[7];
    const float* W_v    = (const float*)d_in[8];
    const float* W_cv   = (const float*)d_in[9];
    const float* W_out  = (const float*)d_in[10];
    const float* b_out  = (const float*)d_in[11];
    const float* W_cout = (const float*)d_in[12];
    const float* b_cout = (const float*)d_in[13];
    float* out = (float*)d_out;

    half_t* ws = (half_t*)d_ws;
    const size_t SEG = 2097152;  // 2*2048*512 halfs = 4 MB
    half_t* xn        = ws;              // seg0: xn, later out_h
    half_t* cn        = ws + 1 * SEG;    // seg1: cn, later ctx_out_h
    half_t* qk        = ws + 2 * SEG;    // [b,h,n,d]
    half_t* cqk       = ws + 3 * SEG;    // [b,h,n,d]
    half_t* v_t       = ws + 4 * SEG;    // [b,h,d,n]
    half_t* cv_t      = ws + 5 * SEG;    // [b,h,d,n]
    half_t* Wt        = ws + 6 * SEG;    // 6 x 512x512 fp16 transposed weights
    half_t* out_h     = xn;              // flash overwrites dead xn
    half_t* ctx_out_h = cn;              // flash overwrites dead cn

    prep_kernel<<<2144, 256, 0, stream>>>(x, ctx, g_x, b_x, g_c, b_c, xn, cn,
                                          W_qk, W_v, W_cqk, W_cv, W_out, W_cout, Wt);
    gemm_in_kernel<<<dim3(32, 4, 4), 256, 0, stream>>>(xn, cn, Wt, qk, v_t, cqk, cv_t);
    flash_kernel<<<dim3(16, 16, 2), 256, 0, stream>>>(qk, cqk, v_t, cv_t, out_h, ctx_out_h);
    gemm_out_kernel<<<dim3(64, 4, 2), 256, 0, stream>>>(out_h, ctx_out_h, Wt, b_out, b_cout, out);
}